// Round 12
// baseline (51.288 us; speedup 1.0000x reference)
//
#include <hip/hip_runtime.h>
#include <stdint.h>

// Problem constants (from reference)
#define BATCH   8192
#define IN_DIM  256
#define OUT_DIM 64
#define NROW    68      // 67 spline rows + 1 silu row per d
#define N_SPLIT 16      // d-splits
#define D_SLICE 16      // d's per block (256/N_SPLIT)
#define D_STAGE 2       // d's staged in LDS at once
#define N_STAGE 8       // stages per block
#define M_BLK   256     // batch rows per block
#define NM      32      // 8192/M_BLK

typedef unsigned int u32;
typedef float f32x4 __attribute__((ext_vector_type(4)));
typedef u32   u32x2 __attribute__((ext_vector_type(2)));
typedef __bf16 bf16x2 __attribute__((ext_vector_type(2)));

#if defined(__has_builtin)
#  if __has_builtin(__builtin_amdgcn_fdot2_f32_bf16)
#    define HAVE_DOT2 1
#  endif
#endif
#ifndef HAVE_DOT2
#  define HAVE_DOT2 0
#endif

__device__ __forceinline__ u32 f2bf(float f) {              // f32 -> bf16 (RNE)
    u32 u = __float_as_uint(f);
    u += 0x7FFFu + ((u >> 16) & 1u);
    return u >> 16;
}
__device__ __forceinline__ float bflo(u32 u) { return __uint_as_float(u << 16); }
__device__ __forceinline__ float bfhi(u32 u) { return __uint_as_float(u & 0xFFFF0000u); }

// {lo, hi} f32 pair -> packed bf16x2 dword (HW v_cvt_pk_bf16_f32 via casts)
__device__ __forceinline__ u32 pkbf(float lo, float hi) {
    bf16x2 v = { (__bf16)lo, (__bf16)hi };
    u32 u;
    __builtin_memcpy(&u, &v, 4);
    return u;
}

// a, b are bf16x2 packed in u32 (element0 = low 16 bits): a0*b0 + a1*b1 + c
__device__ __forceinline__ float dot2bf(u32 a, u32 b, float c) {
#if HAVE_DOT2
    bf16x2 av, bv;
    __builtin_memcpy(&av, &a, 4);
    __builtin_memcpy(&bv, &b, 4);
    return __builtin_amdgcn_fdot2_f32_bf16(av, bv, c, false);
#else
    return fmaf(bflo(a), bflo(b), fmaf(bfhi(a), bfhi(b), c));
#endif
}

// knot t[i], i in [0,70]: 3 clamped zeros, linspace(0,1,65), 3 clamped ones.
__device__ __forceinline__ float knotf(int i) {
    return fminf(1.f, fmaxf(0.f, (float)(i - 3) * 0.015625f));
}

// Windowed Cox-de Boor (degree 3). Record: {c0|c1, c2|c3 (bf16x2), silu f32, s}
__device__ __forceinline__ void make_record(float x, u32 rec[4]) {
    int s = (int)floorf(x * 64.f);
    s = max(0, min(63, s));
    const int m = s + 3;
    float N0 = 1.f, N1, N2, N3;
    const float l1 = x - knotf(m);
    const float r1 = knotf(m + 1) - x;
    {
        float tmp = N0 / (r1 + l1);
        N0 = r1 * tmp;
        N1 = l1 * tmp;
    }
    const float l2 = x - knotf(m - 1);
    const float r2 = knotf(m + 2) - x;
    {
        float tmp = N0 / (r1 + l2);
        N0 = r1 * tmp;
        float saved = l2 * tmp;
        tmp = N1 / (r2 + l1);
        N1 = saved + r2 * tmp;
        N2 = l1 * tmp;
    }
    const float l3 = x - knotf(m - 2);
    const float r3 = knotf(m + 3) - x;
    {
        float tmp = N0 / (r1 + l3);
        N0 = r1 * tmp;
        float saved = l3 * tmp;
        tmp = N1 / (r2 + l2);
        N1 = saved + r2 * tmp;
        saved = l2 * tmp;
        tmp = N2 / (r3 + l1);
        N2 = saved + r3 * tmp;
        N3 = l1 * tmp;
    }
    const float silu = x / (1.f + __expf(-x));
    rec[0] = f2bf(N0) | (f2bf(N1) << 16);
    rec[1] = f2bf(N2) | (f2bf(N3) << 16);
    rec[2] = __float_as_uint(silu);
    rec[3] = (u32)s;
}

// LDS layout (44608 B). Pair-row stride = 272 B (68 dwords): 68 mod 32 = 4, so
// the 128-B gather stripe of pair-row s STARTS at bank (4s mod 32) -- octets
// with different s no longer all start at bank 0 (the R6/R11 residual-conflict
// cause: stride 256 => every stripe started at bank 0, cross-octet phasing
// piled 4-deep on the low banks, SQ_LDS_BANK_CONFLICT=4.19M ~ +2.9cyc/gather).
//   [0, 35904):        pair tables, 2 d's: per d 66 pair-rows x 64 bf16x2,
//                      row stride 272 B (256 data + 16 pad).
//                      wpair[d][r][o] = {w[r][o], w[r+1][o]}
//   [35904, 36416):    silu rows (w row 67) as f32[64] per d (2 x 256 B)
//   [36416, 44608):    coeff records [2 dl][256 r] x 16 B
#define ROW_STRIDE 272
#define TAB_D      17952     // 66 * 272
#define SILU_OFF   35904
#define REC_OFF    36416
#define LDS_U4     2788

// launch_bounds empirics on this ROCm (R1/R3/R5-R10 calibration): 2nd arg acts
// as min BLOCKS/CU; VGPR cap = 512/(2*arg) for 512-thread blocks. arg=3 -> 85
// cap, demand ~44 -> no spill, VGPR<=64 keeps the 32-wave bracket.
// Structural probes R7 (4 blocks/CU), R9 (dbuf+prefetch, cap128), R10 (same,
// cap85) all regressed: no register headroom for deeper pipelining here.
__global__ __launch_bounds__(512, 3)
void kan_main(const float* __restrict__ X, const float* __restrict__ W,
              void* __restrict__ outbuf, int useAtomic) {
    __shared__ uint4 smem4[LDS_U4];
    char* sm = (char*)smem4;

    const int mb  = blockIdx.x;          // 0..31
    const int sp  = blockIdx.y;          // 0..15
    const int tid = threadIdx.x;
    const int r0  = mb * M_BLK;
    const int d0  = sp * D_SLICE;

    const int lane = tid & 63;
    const int wv   = tid >> 6;           // wave 0..7
    const int sub  = lane & 7;           // output-chunk selector
    const int g    = lane >> 3;          // row-in-round 0..7
    const int rb   = wv * 32;            // wave's local row base

    // lane covers outputs {sub*4..+3} and {32+sub*4..+3}
    float acc[4][8];
#pragma unroll
    for (int t = 0; t < 4; ++t)
#pragma unroll
        for (int k = 0; k < 8; ++k) acc[t][k] = 0.f;

    for (int st = 0; st < N_STAGE; ++st) {
        const int ds = d0 + st * D_STAGE;
        __syncthreads();   // prev stage's readers done before overwrite

        // ---- stage pair table: 2 d x 66 pair-rows x 16 uint4 ----
        {
            const float* wbase = W + (size_t)ds * (NROW * OUT_DIM);
            for (int i = tid; i < 2 * 66 * 16; i += 512) {
                const int dl  = (i >= 1056) ? 1 : 0;
                const int rem = i - dl * 1056;
                const int r   = rem >> 4;
                const int c16 = rem & 15;          // 16-B chunk in row (4 outputs)
                const float* p = wbase + (size_t)dl * (NROW * OUT_DIM)
                               + r * OUT_DIM + (c16 << 2);
                float4 va = *(const float4*)p;             // row r
                float4 vb = *(const float4*)(p + OUT_DIM); // row r+1
                const int byte = dl * TAB_D + r * ROW_STRIDE + (c16 << 4);
                *(uint4*)(sm + byte) = make_uint4(pkbf(va.x, vb.x), pkbf(va.y, vb.y),
                                                  pkbf(va.z, vb.z), pkbf(va.w, vb.w));
            }
            // silu rows (w row 67) as f32: tail 64 threads, 2 d's each
            if (tid >= 448) {
                const int j = tid - 448;           // 0..63
#pragma unroll
                for (int dl = 0; dl < 2; ++dl) {
                    *(float*)(sm + SILU_OFF + dl * 256 + j * 4) =
                        wbase[(size_t)dl * (NROW * OUT_DIM) + 67 * OUT_DIM + j];
                }
            }
        }
        // ---- coeff records: 256 rows x 2 d, one per thread ----
        {
            const int r  = tid & 255;
            const int dh = tid >> 8;     // 0..1
            const float x = X[(size_t)(r0 + r) * IN_DIM + ds + dh];
            u32 rec[4];
            make_record(x, rec);
            *(uint4*)(sm + REC_OFF + ((dh * 256 + r) << 4)) =
                make_uint4(rec[0], rec[1], rec[2], rec[3]);
        }
        __syncthreads();

        // ---- gather + dot2 over 2 d's x 32 rows/wave ----
#pragma unroll
        for (int dl = 0; dl < D_STAGE; ++dl) {
            const int tb = dl * TAB_D;
            // silu weight row, f32, two conflict-free stripes
            const f32x4 w67a = *(const f32x4*)(sm + SILU_OFF + dl * 256 + sub * 16);
            const f32x4 w67b = *(const f32x4*)(sm + SILU_OFF + dl * 256 + 128 + sub * 16);
#pragma unroll
            for (int t = 0; t < 4; ++t) {
                const uint4 rec = *(const uint4*)(sm + REC_OFF +
                                                  ((dl * 256 + rb + t * 8 + g) << 4));
                const u32 c01 = rec.x, c23 = rec.y;
                const float silu = __uint_as_float(rec.z);
                const int s = (int)rec.w;
                const char* r1 = sm + tb + s * ROW_STRIDE + sub * 16;        // row s
                const char* r2 = sm + tb + (s + 2) * ROW_STRIDE + sub * 16;  // row s+2
                const uint4 p1  = *(const uint4*)(r1);          // outputs sub*4..+3
                const uint4 p1b = *(const uint4*)(r1 + 128);    // outputs 32+sub*4..+3
                const uint4 p2  = *(const uint4*)(r2);
                const uint4 p2b = *(const uint4*)(r2 + 128);
                acc[t][0] = dot2bf(c23, p2.x,  dot2bf(c01, p1.x,  acc[t][0]));
                acc[t][1] = dot2bf(c23, p2.y,  dot2bf(c01, p1.y,  acc[t][1]));
                acc[t][2] = dot2bf(c23, p2.z,  dot2bf(c01, p1.z,  acc[t][2]));
                acc[t][3] = dot2bf(c23, p2.w,  dot2bf(c01, p1.w,  acc[t][3]));
                acc[t][4] = dot2bf(c23, p2b.x, dot2bf(c01, p1b.x, acc[t][4]));
                acc[t][5] = dot2bf(c23, p2b.y, dot2bf(c01, p1b.y, acc[t][5]));
                acc[t][6] = dot2bf(c23, p2b.z, dot2bf(c01, p1b.z, acc[t][6]));
                acc[t][7] = dot2bf(c23, p2b.w, dot2bf(c01, p1b.w, acc[t][7]));
                acc[t][0] = fmaf(silu, w67a.x, acc[t][0]);
                acc[t][1] = fmaf(silu, w67a.y, acc[t][1]);
                acc[t][2] = fmaf(silu, w67a.z, acc[t][2]);
                acc[t][3] = fmaf(silu, w67a.w, acc[t][3]);
                acc[t][4] = fmaf(silu, w67b.x, acc[t][4]);
                acc[t][5] = fmaf(silu, w67b.y, acc[t][5]);
                acc[t][6] = fmaf(silu, w67b.z, acc[t][6]);
                acc[t][7] = fmaf(silu, w67b.w, acc[t][7]);
            }
        }
    }

    // ---- emit partials as bf16 planes (streamed once, read once) ----
    if (!useAtomic) {
        char* wsp = (char*)outbuf + (size_t)sp * (BATCH * OUT_DIM * 2);
#pragma unroll
        for (int t = 0; t < 4; ++t) {
            const int R = r0 + rb + t * 8 + g;
            u32x2 lo = { pkbf(acc[t][0], acc[t][1]), pkbf(acc[t][2], acc[t][3]) };
            u32x2 hi = { pkbf(acc[t][4], acc[t][5]), pkbf(acc[t][6], acc[t][7]) };
            __builtin_nontemporal_store(lo, (u32x2*)(wsp + (size_t)R * 128 + sub * 8));
            __builtin_nontemporal_store(hi, (u32x2*)(wsp + (size_t)R * 128 + 64 + sub * 8));
        }
    } else {
        float* out = (float*)outbuf;
#pragma unroll
        for (int t = 0; t < 4; ++t) {
            const int R = r0 + rb + t * 8 + g;
#pragma unroll
            for (int k = 0; k < 4; ++k) {
                atomicAdd(out + (size_t)R * 64 + sub * 4 + k, acc[t][k]);
                atomicAdd(out + (size_t)R * 64 + 32 + sub * 4 + k, acc[t][k + 4]);
            }
        }
    }
}

__global__ __launch_bounds__(256)
void kan_reduce(const u32* __restrict__ ws, float* __restrict__ out) {
    const int i = blockIdx.x * 256 + threadIdx.x;   // u32x2 index (4 bf16), 131072
    const u32x2* w2 = (const u32x2*)ws;
    float a0 = 0.f, a1 = 0.f, a2 = 0.f, a3 = 0.f;
#pragma unroll
    for (int s = 0; s < N_SPLIT; ++s) {
        u32x2 v = __builtin_nontemporal_load(
            &w2[(size_t)s * (BATCH * OUT_DIM / 4) + i]);
        a0 += bflo(v.x); a1 += bfhi(v.x);
        a2 += bflo(v.y); a3 += bfhi(v.y);
    }
    f32x4 r = { a0, a1, a2, a3 };
    *(f32x4*)(out + (size_t)i * 4) = r;
}

extern "C" void kernel_launch(void* const* d_in, const int* in_sizes, int n_in,
                              void* d_out, int out_size, void* d_ws, size_t ws_size,
                              hipStream_t stream) {
    const float* X = (const float*)d_in[0];
    const float* W = (const float*)d_in[1];
    float* out = (float*)d_out;
    const size_t need = (size_t)N_SPLIT * BATCH * OUT_DIM * 2;   // bf16 planes
    dim3 grid(NM, N_SPLIT);
    if (ws_size >= need) {
        kan_main<<<grid, 512, 0, stream>>>(X, W, d_ws, 0);
        kan_reduce<<<(BATCH * OUT_DIM / 4) / 256, 256, 0, stream>>>((const u32*)d_ws, out);
    } else {
        (void)hipMemsetAsync(d_out, 0, (size_t)out_size * sizeof(float), stream);
        kan_main<<<grid, 512, 0, stream>>>(X, W, d_out, 1);
    }
}

// Round 13
// 49.174 us; speedup vs baseline: 1.0430x; 1.0430x over previous
//
#include <hip/hip_runtime.h>
#include <stdint.h>

// Problem constants (from reference)
#define BATCH   8192
#define IN_DIM  256
#define OUT_DIM 64
#define NROW    68      // 67 spline rows + 1 silu row per d
#define N_SPLIT 16      // d-splits
#define D_SLICE 16      // d's per block (256/N_SPLIT)
#define D_STAGE 2       // d's staged in LDS at once
#define N_STAGE 8       // stages per block
#define M_BLK   256     // batch rows per block
#define NM      32      // 8192/M_BLK

typedef unsigned int u32;
typedef float f32x4 __attribute__((ext_vector_type(4)));
typedef u32   u32x2 __attribute__((ext_vector_type(2)));
typedef __bf16 bf16x2 __attribute__((ext_vector_type(2)));

#if defined(__has_builtin)
#  if __has_builtin(__builtin_amdgcn_fdot2_f32_bf16)
#    define HAVE_DOT2 1
#  endif
#endif
#ifndef HAVE_DOT2
#  define HAVE_DOT2 0
#endif

__device__ __forceinline__ u32 f2bf(float f) {              // f32 -> bf16 (RNE)
    u32 u = __float_as_uint(f);
    u += 0x7FFFu + ((u >> 16) & 1u);
    return u >> 16;
}
__device__ __forceinline__ float bflo(u32 u) { return __uint_as_float(u << 16); }
__device__ __forceinline__ float bfhi(u32 u) { return __uint_as_float(u & 0xFFFF0000u); }

// {lo, hi} f32 pair -> packed bf16x2 dword (HW v_cvt_pk_bf16_f32 via casts)
__device__ __forceinline__ u32 pkbf(float lo, float hi) {
    bf16x2 v = { (__bf16)lo, (__bf16)hi };
    u32 u;
    __builtin_memcpy(&u, &v, 4);
    return u;
}

// a, b are bf16x2 packed in u32 (element0 = low 16 bits): a0*b0 + a1*b1 + c
__device__ __forceinline__ float dot2bf(u32 a, u32 b, float c) {
#if HAVE_DOT2
    bf16x2 av, bv;
    __builtin_memcpy(&av, &a, 4);
    __builtin_memcpy(&bv, &b, 4);
    return __builtin_amdgcn_fdot2_f32_bf16(av, bv, c, false);
#else
    return fmaf(bflo(a), bflo(b), fmaf(bfhi(a), bfhi(b), c));
#endif
}

// knot t[i], i in [0,70]: 3 clamped zeros, linspace(0,1,65), 3 clamped ones.
__device__ __forceinline__ float knotf(int i) {
    return fminf(1.f, fmaxf(0.f, (float)(i - 3) * 0.015625f));
}

// Windowed Cox-de Boor (degree 3). Record: {c0|c1, c2|c3 (bf16x2), silu f32, s}
__device__ __forceinline__ void make_record(float x, u32 rec[4]) {
    int s = (int)floorf(x * 64.f);
    s = max(0, min(63, s));
    const int m = s + 3;
    float N0 = 1.f, N1, N2, N3;
    const float l1 = x - knotf(m);
    const float r1 = knotf(m + 1) - x;
    {
        float tmp = N0 / (r1 + l1);
        N0 = r1 * tmp;
        N1 = l1 * tmp;
    }
    const float l2 = x - knotf(m - 1);
    const float r2 = knotf(m + 2) - x;
    {
        float tmp = N0 / (r1 + l2);
        N0 = r1 * tmp;
        float saved = l2 * tmp;
        tmp = N1 / (r2 + l1);
        N1 = saved + r2 * tmp;
        N2 = l1 * tmp;
    }
    const float l3 = x - knotf(m - 2);
    const float r3 = knotf(m + 3) - x;
    {
        float tmp = N0 / (r1 + l3);
        N0 = r1 * tmp;
        float saved = l3 * tmp;
        tmp = N1 / (r2 + l2);
        N1 = saved + r2 * tmp;
        saved = l2 * tmp;
        tmp = N2 / (r3 + l1);
        N2 = saved + r3 * tmp;
        N3 = l1 * tmp;
    }
    const float silu = x / (1.f + __expf(-x));
    rec[0] = f2bf(N0) | (f2bf(N1) << 16);
    rec[1] = f2bf(N2) | (f2bf(N3) << 16);
    rec[2] = __float_as_uint(silu);
    rec[3] = (u32)s;
}

// LDS layout (42496 B), all LINEAR (conflict-freedom is structural: every
// 8-lane octet of a gather read covers one contiguous 128-B bank stripe):
//   [0, 33792):        pair tables, 2 d's: per d 66 pair-rows x 64 bf16x2,
//                      row stride 256 B. wpair[d][r][o] = {w[r][o], w[r+1][o]}
//   [33792, 34304):    silu rows (w row 67) as f32[64] per d (2 x 256 B)
//   [34304, 42496):    coeff records [2 dl][256 r] x 16 B
// R12 note: staggering row stride to 272 B INCREASED conflicts (4.19M->5.98M)
// and time (+2 us) -- stride-256 linear is the best measured layout.
#define TAB_D     16896
#define SILU_OFF  33792
#define REC_OFF   34304
#define LDS_U4    2656

// launch_bounds empirics on this ROCm (R1/R3/R5-R10 calibration): 2nd arg acts
// as min BLOCKS/CU; VGPR cap = 512/(2*arg) for 512-thread blocks. arg=3 -> 85
// cap, demand here is ~44 -> no spill, and VGPR<=64 keeps the 32-wave bracket.
// Structural probes R7 (4 blocks/CU), R9 (dbuf+prefetch, cap128), R10 (same,
// cap85), R12 (stride stagger) all regressed: this 2-barrier loop is the
// measured optimum of the gather-dot2 formulation (49.2-49.3 us).
__global__ __launch_bounds__(512, 3)
void kan_main(const float* __restrict__ X, const float* __restrict__ W,
              void* __restrict__ outbuf, int useAtomic) {
    __shared__ uint4 smem4[LDS_U4];
    char* sm = (char*)smem4;

    const int mb  = blockIdx.x;          // 0..31
    const int sp  = blockIdx.y;          // 0..15
    const int tid = threadIdx.x;
    const int r0  = mb * M_BLK;
    const int d0  = sp * D_SLICE;

    const int lane = tid & 63;
    const int wv   = tid >> 6;           // wave 0..7
    const int sub  = lane & 7;           // output-chunk selector
    const int g    = lane >> 3;          // row-in-round 0..7
    const int rb   = wv * 32;            // wave's local row base

    // lane covers outputs {sub*4..+3} and {32+sub*4..+3}
    float acc[4][8];
#pragma unroll
    for (int t = 0; t < 4; ++t)
#pragma unroll
        for (int k = 0; k < 8; ++k) acc[t][k] = 0.f;

    for (int st = 0; st < N_STAGE; ++st) {
        const int ds = d0 + st * D_STAGE;
        __syncthreads();   // prev stage's readers done before overwrite

        // ---- stage pair table: 2 d x 66 pair-rows x 16 uint4, linear ----
        {
            const float* wbase = W + (size_t)ds * (NROW * OUT_DIM);
            for (int i = tid; i < 2 * 66 * 16; i += 512) {
                const int dl  = (i >= 1056) ? 1 : 0;
                const int rem = i - dl * 1056;
                const int r   = rem >> 4;
                const int c16 = rem & 15;          // 16-B chunk in row (4 outputs)
                const float* p = wbase + (size_t)dl * (NROW * OUT_DIM)
                               + r * OUT_DIM + (c16 << 2);
                float4 va = *(const float4*)p;             // row r
                float4 vb = *(const float4*)(p + OUT_DIM); // row r+1
                const int byte = dl * TAB_D + r * 256 + (c16 << 4);
                *(uint4*)(sm + byte) = make_uint4(pkbf(va.x, vb.x), pkbf(va.y, vb.y),
                                                  pkbf(va.z, vb.z), pkbf(va.w, vb.w));
            }
            // silu rows (w row 67) as f32: tail 64 threads, 2 d's each
            if (tid >= 448) {
                const int j = tid - 448;           // 0..63
#pragma unroll
                for (int dl = 0; dl < 2; ++dl) {
                    *(float*)(sm + SILU_OFF + dl * 256 + j * 4) =
                        wbase[(size_t)dl * (NROW * OUT_DIM) + 67 * OUT_DIM + j];
                }
            }
        }
        // ---- coeff records: 256 rows x 2 d, one per thread ----
        {
            const int r  = tid & 255;
            const int dh = tid >> 8;     // 0..1
            const float x = X[(size_t)(r0 + r) * IN_DIM + ds + dh];
            u32 rec[4];
            make_record(x, rec);
            *(uint4*)(sm + REC_OFF + ((dh * 256 + r) << 4)) =
                make_uint4(rec[0], rec[1], rec[2], rec[3]);
        }
        __syncthreads();

        // ---- gather + dot2 over 2 d's x 32 rows/wave ----
#pragma unroll
        for (int dl = 0; dl < D_STAGE; ++dl) {
            const int tb = dl * TAB_D;
            // silu weight row, f32, two conflict-free stripes
            const f32x4 w67a = *(const f32x4*)(sm + SILU_OFF + dl * 256 + sub * 16);
            const f32x4 w67b = *(const f32x4*)(sm + SILU_OFF + dl * 256 + 128 + sub * 16);
#pragma unroll
            for (int t = 0; t < 4; ++t) {
                const uint4 rec = *(const uint4*)(sm + REC_OFF +
                                                  ((dl * 256 + rb + t * 8 + g) << 4));
                const u32 c01 = rec.x, c23 = rec.y;
                const float silu = __uint_as_float(rec.z);
                const int s = (int)rec.w;
                const char* r1 = sm + tb + s * 256 + sub * 16;        // pair-row s
                const char* r2 = sm + tb + (s + 2) * 256 + sub * 16;  // pair-row s+2
                const uint4 p1  = *(const uint4*)(r1);          // outputs sub*4..+3
                const uint4 p1b = *(const uint4*)(r1 + 128);    // outputs 32+sub*4..+3
                const uint4 p2  = *(const uint4*)(r2);
                const uint4 p2b = *(const uint4*)(r2 + 128);
                acc[t][0] = dot2bf(c23, p2.x,  dot2bf(c01, p1.x,  acc[t][0]));
                acc[t][1] = dot2bf(c23, p2.y,  dot2bf(c01, p1.y,  acc[t][1]));
                acc[t][2] = dot2bf(c23, p2.z,  dot2bf(c01, p1.z,  acc[t][2]));
                acc[t][3] = dot2bf(c23, p2.w,  dot2bf(c01, p1.w,  acc[t][3]));
                acc[t][4] = dot2bf(c23, p2b.x, dot2bf(c01, p1b.x, acc[t][4]));
                acc[t][5] = dot2bf(c23, p2b.y, dot2bf(c01, p1b.y, acc[t][5]));
                acc[t][6] = dot2bf(c23, p2b.z, dot2bf(c01, p1b.z, acc[t][6]));
                acc[t][7] = dot2bf(c23, p2b.w, dot2bf(c01, p1b.w, acc[t][7]));
                acc[t][0] = fmaf(silu, w67a.x, acc[t][0]);
                acc[t][1] = fmaf(silu, w67a.y, acc[t][1]);
                acc[t][2] = fmaf(silu, w67a.z, acc[t][2]);
                acc[t][3] = fmaf(silu, w67a.w, acc[t][3]);
                acc[t][4] = fmaf(silu, w67b.x, acc[t][4]);
                acc[t][5] = fmaf(silu, w67b.y, acc[t][5]);
                acc[t][6] = fmaf(silu, w67b.z, acc[t][6]);
                acc[t][7] = fmaf(silu, w67b.w, acc[t][7]);
            }
        }
    }

    // ---- emit partials as bf16 planes (streamed once, read once) ----
    if (!useAtomic) {
        char* wsp = (char*)outbuf + (size_t)sp * (BATCH * OUT_DIM * 2);
#pragma unroll
        for (int t = 0; t < 4; ++t) {
            const int R = r0 + rb + t * 8 + g;
            u32x2 lo = { pkbf(acc[t][0], acc[t][1]), pkbf(acc[t][2], acc[t][3]) };
            u32x2 hi = { pkbf(acc[t][4], acc[t][5]), pkbf(acc[t][6], acc[t][7]) };
            __builtin_nontemporal_store(lo, (u32x2*)(wsp + (size_t)R * 128 + sub * 8));
            __builtin_nontemporal_store(hi, (u32x2*)(wsp + (size_t)R * 128 + 64 + sub * 8));
        }
    } else {
        float* out = (float*)outbuf;
#pragma unroll
        for (int t = 0; t < 4; ++t) {
            const int R = r0 + rb + t * 8 + g;
#pragma unroll
            for (int k = 0; k < 4; ++k) {
                atomicAdd(out + (size_t)R * 64 + sub * 4 + k, acc[t][k]);
                atomicAdd(out + (size_t)R * 64 + 32 + sub * 4 + k, acc[t][k + 4]);
            }
        }
    }
}

__global__ __launch_bounds__(256)
void kan_reduce(const u32* __restrict__ ws, float* __restrict__ out) {
    const int i = blockIdx.x * 256 + threadIdx.x;   // u32x2 index (4 bf16), 131072
    const u32x2* w2 = (const u32x2*)ws;
    float a0 = 0.f, a1 = 0.f, a2 = 0.f, a3 = 0.f;
#pragma unroll
    for (int s = 0; s < N_SPLIT; ++s) {
        u32x2 v = __builtin_nontemporal_load(
            &w2[(size_t)s * (BATCH * OUT_DIM / 4) + i]);
        a0 += bflo(v.x); a1 += bfhi(v.x);
        a2 += bflo(v.y); a3 += bfhi(v.y);
    }
    f32x4 r = { a0, a1, a2, a3 };
    *(f32x4*)(out + (size_t)i * 4) = r;
}

extern "C" void kernel_launch(void* const* d_in, const int* in_sizes, int n_in,
                              void* d_out, int out_size, void* d_ws, size_t ws_size,
                              hipStream_t stream) {
    const float* X = (const float*)d_in[0];
    const float* W = (const float*)d_in[1];
    float* out = (float*)d_out;
    const size_t need = (size_t)N_SPLIT * BATCH * OUT_DIM * 2;   // bf16 planes
    dim3 grid(NM, N_SPLIT);
    if (ws_size >= need) {
        kan_main<<<grid, 512, 0, stream>>>(X, W, d_ws, 0);
        kan_reduce<<<(BATCH * OUT_DIM / 4) / 256, 256, 0, stream>>>((const u32*)d_ws, out);
    } else {
        (void)hipMemsetAsync(d_out, 0, (size_t)out_size * sizeof(float), stream);
        kan_main<<<grid, 512, 0, stream>>>(X, W, d_out, 1);
    }
}